// Round 2
// baseline (523.692 us; speedup 1.0000x reference)
//
#include <hip/hip_runtime.h>
#include <hip/hip_bf16.h>
#include <stdint.h>

// MHA forward, fp32 in/out (bf16 internal), MI355X gfx950.
// detect dtype -> convert x/W to bf16 -> rope table -> fused QKV GEMM+RoPE -> flash attn -> O-proj GEMM.

typedef __attribute__((ext_vector_type(8))) short short8;
typedef __attribute__((ext_vector_type(4))) float floatx4;

#define MFMA_BF16(a, b, c) __builtin_amdgcn_mfma_f32_16x16x32_bf16((a), (b), (c), 0, 0, 0)

__device__ __forceinline__ unsigned short f2bf(float f) {
    unsigned int u; __builtin_memcpy(&u, &f, 4);
    unsigned int r = (u + 0x7fffu + ((u >> 16) & 1u)) >> 16;
    return (unsigned short)r;
}
__device__ __forceinline__ float bf2f(unsigned short s) {
    unsigned int u = (unsigned int)s << 16;
    float f; __builtin_memcpy(&f, &u, 4);
    return f;
}

__device__ __forceinline__ void load_lds16(const unsigned short* g, unsigned short* l) {
    __builtin_amdgcn_global_load_lds(
        (const __attribute__((address_space(1))) void*)g,
        (__attribute__((address_space(3))) void*)l, 16, 0, 0);
}

// ---------------- dtype detector: flag=1 if x is fp32, 0 if bf16 ----------------
__global__ void detect_k(const unsigned short* __restrict__ xr, int* __restrict__ flag) {
    int t = threadIdx.x;  // one block of 256
    int bad = 0;
    for (int i = t; i < 4096; i += 256) {
        float v = bf2f(xr[i]);
        if (!(__builtin_fabsf(v) < 1e10f)) bad = 1;  // NaN/Inf/huge => fp32 source
    }
    __shared__ int r[4];
    unsigned long long m = __ballot(bad != 0);
    if ((t & 63) == 0) r[t >> 6] = (m != 0ull) ? 1 : 0;
    __syncthreads();
    if (t == 0) flag[0] = (r[0] | r[1] | r[2] | r[3]);
}

// ---------------- x convert: dst bf16 = src (fp32 or bf16 per flag) ----------------
__global__ void cvt_x_k(const void* __restrict__ src, unsigned short* __restrict__ dst,
                        const int* __restrict__ flag, int n) {
    int i = blockIdx.x * blockDim.x + threadIdx.x;
    if (i >= n) return;
    float v = (*flag) ? ((const float*)src)[i] : bf2f(((const unsigned short*)src)[i]);
    dst[i] = f2bf(v);
}

// ---------------- weight transpose+convert: dst[n][k] = cvt(src[k][n]), 1024x1024 ----------------
__global__ void transpose_k(const void* __restrict__ src, unsigned short* __restrict__ dst,
                            const int* __restrict__ flag) {
    __shared__ unsigned short tile[32][33];
    const int n = 1024;
    bool f32 = (*flag) != 0;
    int bx = blockIdx.x * 32, by = blockIdx.y * 32;
    int tx = threadIdx.x, ty = threadIdx.y;  // 32 x 8
#pragma unroll
    for (int j = 0; j < 32; j += 8) {
        size_t idx = (size_t)(by + ty + j) * n + bx + tx;
        float v = f32 ? ((const float*)src)[idx] : bf2f(((const unsigned short*)src)[idx]);
        tile[ty + j][tx] = f2bf(v);
    }
    __syncthreads();
#pragma unroll
    for (int j = 0; j < 32; j += 8)
        dst[(size_t)(bx + ty + j) * n + by + tx] = tile[tx][ty + j];
}

// ---------------- rope table: tab[pos*32 + j] = (cos, sin)(pos * theta^(-2j/64)) ----------------
__global__ void rope_tab_k(float2* __restrict__ tab) {
    int i = blockIdx.x * blockDim.x + threadIdx.x;
    if (i >= 2048 * 32) return;
    int pos = i >> 5, j = i & 31;
    float freq = exp2f(-(float)(2 * j) * (1.0f / 64.0f) * 13.287712379549449f);  // log2(10000)
    float a = (float)pos * freq;
    tab[i] = make_float2(cosf(a), sinf(a));
}

// ---------------- GEMM: C(MxN) = A(MxK) * W, Bt = W^T (N x K), bf16 MFMA, K=1024 ----------------
// MODE 0: O-proj epilogue -> d_out (fp32 or bf16 per flag), N=1024
// MODE 1: QKV epilogue: N=3072, split Q/K/V (bf16), RoPE on Q,K
template <int MODE>
__global__ __launch_bounds__(256) void gemm_bt(
    const unsigned short* __restrict__ A,
    const unsigned short* __restrict__ Bt,
    void* __restrict__ C0,             // MODE0: out.  MODE1: Qb
    unsigned short* __restrict__ C1,   // MODE1: Kb
    unsigned short* __restrict__ C2,   // MODE1: Vb
    const float2* __restrict__ tab,
    const int* __restrict__ flag) {
    const int K = 1024;
    __shared__ __align__(16) unsigned short Al[128 * 32];
    __shared__ __align__(16) unsigned short Bl[128 * 32];

    int m0 = blockIdx.y * 128;
    int n0 = blockIdx.x * 128;
    int t = threadIdx.x;
    int lane = t & 63, w = t >> 6;
    int quad = lane >> 4, l15 = lane & 15;
    int wm = (w >> 1) * 64, wn = (w & 1) * 64;

    floatx4 acc[4][4];
#pragma unroll
    for (int i = 0; i < 4; i++)
#pragma unroll
        for (int j = 0; j < 4; j++) acc[i][j] = (floatx4){0.f, 0.f, 0.f, 0.f};

    for (int k0 = 0; k0 < K; k0 += 32) {
#pragma unroll
        for (int c = 0; c < 2; c++) {
            int row = w * 32 + c * 16 + (lane >> 2);
            load_lds16(A + (size_t)(m0 + row) * K + k0 + (lane & 3) * 8,
                       &Al[(w * 32 + c * 16) * 32]);
        }
#pragma unroll
        for (int c = 0; c < 2; c++) {
            int row = w * 32 + c * 16 + (lane >> 2);
            load_lds16(Bt + (size_t)(n0 + row) * K + k0 + (lane & 3) * 8,
                       &Bl[(w * 32 + c * 16) * 32]);
        }
        asm volatile("s_waitcnt vmcnt(0)" ::: "memory");
        __syncthreads();

        short8 af[4], bfr[4];
#pragma unroll
        for (int i = 0; i < 4; i++)
            af[i] = *(const short8*)&Al[(wm + i * 16 + l15) * 32 + quad * 8];
#pragma unroll
        for (int j = 0; j < 4; j++)
            bfr[j] = *(const short8*)&Bl[(wn + j * 16 + l15) * 32 + quad * 8];
#pragma unroll
        for (int i = 0; i < 4; i++)
#pragma unroll
            for (int j = 0; j < 4; j++) acc[i][j] = MFMA_BF16(af[i], bfr[j], acc[i][j]);
        __syncthreads();
    }

    bool out_f32 = MODE == 0 ? ((*flag) != 0) : false;
#pragma unroll
    for (int i = 0; i < 4; i++) {
#pragma unroll
        for (int j = 0; j < 4; j++) {
#pragma unroll
            for (int r = 0; r < 4; r++) {
                int row = m0 + wm + i * 16 + quad * 4 + r;
                int col = n0 + wn + j * 16 + l15;
                float v = acc[i][j][r];
                if (MODE == 0) {
                    size_t idx = (size_t)row * 1024 + col;
                    if (out_f32) ((float*)C0)[idx] = v;
                    else ((unsigned short*)C0)[idx] = f2bf(v);
                } else {
                    int b = row >> 11, s = row & 2047;
                    int which = col >> 10, nn = col & 1023;  // uniform per block
                    size_t idx = ((size_t)(b * 2048 + s)) * 1024 + nn;
                    if (which == 2) {
                        C2[idx] = f2bf(v);
                    } else {
                        int d = nn & 63;
                        float pv = __shfl_xor(v, 1);
                        float2 cs = tab[(s << 5) + (d >> 1)];
                        float o = (d & 1) ? (v * cs.x + pv * cs.y) : (v * cs.x - pv * cs.y);
                        (which == 0 ? (unsigned short*)C0 : C1)[idx] = f2bf(o);
                    }
                }
            }
        }
    }
}

// ---------------- flash attention ----------------
// grid: (B*H, S/64). block 256 = 4 waves, wave w handles 16 q rows.
// Q/K/V in (B,S,D) layout (head h = cols h*64..h*64+63). Causal. scale=0.125.
__global__ __launch_bounds__(256) void flash_k(
    const unsigned short* __restrict__ Qb,
    const unsigned short* __restrict__ Kb,
    const unsigned short* __restrict__ Vb,
    unsigned short* __restrict__ A2) {
    __shared__ __align__(16) unsigned short Kl[32 * 64];
    __shared__ __align__(16) unsigned short Vt_l[64 * 32];
    __shared__ __align__(16) unsigned short Pl[4][16 * 32];

    int bh = blockIdx.x;
    int b = bh >> 4, h = bh & 15;
    int q0 = blockIdx.y * 64;
    int t = threadIdx.x, lane = t & 63, w = t >> 6;
    int quad = lane >> 4, l15 = lane & 15;

    const size_t base = ((size_t)b * 2048) * 1024 + h * 64;
    const unsigned short* qbase = Qb + base;
    const unsigned short* kbase = Kb + base;
    const unsigned short* vbase = Vb + base;

    int qr = q0 + w * 16 + l15;
    short8 qa0 = *(const short8*)(qbase + (size_t)qr * 1024 + quad * 8);
    short8 qa1 = *(const short8*)(qbase + (size_t)qr * 1024 + 32 + quad * 8);

    floatx4 o0 = {0.f, 0.f, 0.f, 0.f}, o1 = o0, o2 = o0, o3 = o0;
    float mr[4] = {-1e30f, -1e30f, -1e30f, -1e30f};
    float lr[4] = {0.f, 0.f, 0.f, 0.f};

    int nkt = (q0 + 64) >> 5;  // 32-wide K tiles covering cols 0..q0+63
    for (int kt = 0; kt < nkt; kt++) {
        int krow0 = kt * 32;
        {   // stage K[32][64] and V^T[64][32]
            int sl = t >> 3, doff = (t & 7) * 8;
            union { short8 v; unsigned short u[8]; } kv, vv;
            kv.v = *(const short8*)(kbase + (size_t)(krow0 + sl) * 1024 + doff);
            *(short8*)&Kl[sl * 64 + doff] = kv.v;
            vv.v = *(const short8*)(vbase + (size_t)(krow0 + sl) * 1024 + doff);
#pragma unroll
            for (int i = 0; i < 8; i++) Vt_l[(doff + i) * 32 + sl] = vv.u[i];
        }
        __syncthreads();

        floatx4 s0 = {0.f, 0.f, 0.f, 0.f}, s1 = s0;
        s0 = MFMA_BF16(qa0, *(const short8*)&Kl[l15 * 64 + quad * 8], s0);
        s0 = MFMA_BF16(qa1, *(const short8*)&Kl[l15 * 64 + 32 + quad * 8], s0);
        s1 = MFMA_BF16(qa0, *(const short8*)&Kl[(16 + l15) * 64 + quad * 8], s1);
        s1 = MFMA_BF16(qa1, *(const short8*)&Kl[(16 + l15) * 64 + 32 + quad * 8], s1);

        int col0 = krow0 + l15, col1 = col0 + 16;
        float alpha[4];
#pragma unroll
        for (int r = 0; r < 4; r++) {
            int rowg = q0 + w * 16 + quad * 4 + r;
            float a0 = s0[r] * 0.125f; if (col0 > rowg) a0 = -1e30f;
            float a1 = s1[r] * 0.125f; if (col1 > rowg) a1 = -1e30f;
            float mx = fmaxf(a0, a1);
#pragma unroll
            for (int off = 1; off < 16; off <<= 1) mx = fmaxf(mx, __shfl_xor(mx, off));
            float mnew = fmaxf(mr[r], mx);
            float al = __expf(mr[r] - mnew);
            mr[r] = mnew;
            alpha[r] = al;
            float p0 = __expf(a0 - mnew), p1 = __expf(a1 - mnew);
            float rs = p0 + p1;
#pragma unroll
            for (int off = 1; off < 16; off <<= 1) rs += __shfl_xor(rs, off);
            lr[r] = lr[r] * al + rs;
            Pl[w][(quad * 4 + r) * 32 + l15] = f2bf(p0);
            Pl[w][(quad * 4 + r) * 32 + 16 + l15] = f2bf(p1);
        }
#pragma unroll
        for (int r = 0; r < 4; r++) {
            o0[r] *= alpha[r]; o1[r] *= alpha[r]; o2[r] *= alpha[r]; o3[r] *= alpha[r];
        }
        short8 pa = *(const short8*)&Pl[w][l15 * 32 + quad * 8];
        o0 = MFMA_BF16(pa, *(const short8*)&Vt_l[(0 * 16 + l15) * 32 + quad * 8], o0);
        o1 = MFMA_BF16(pa, *(const short8*)&Vt_l[(1 * 16 + l15) * 32 + quad * 8], o1);
        o2 = MFMA_BF16(pa, *(const short8*)&Vt_l[(2 * 16 + l15) * 32 + quad * 8], o2);
        o3 = MFMA_BF16(pa, *(const short8*)&Vt_l[(3 * 16 + l15) * 32 + quad * 8], o3);
        __syncthreads();
    }

    unsigned short* obase = A2 + base;
#pragma unroll
    for (int r = 0; r < 4; r++) {
        int rowg = q0 + w * 16 + quad * 4 + r;
        float inv = 1.0f / lr[r];
        obase[(size_t)rowg * 1024 + 0  + l15] = f2bf(o0[r] * inv);
        obase[(size_t)rowg * 1024 + 16 + l15] = f2bf(o1[r] * inv);
        obase[(size_t)rowg * 1024 + 32 + l15] = f2bf(o2[r] * inv);
        obase[(size_t)rowg * 1024 + 48 + l15] = f2bf(o3[r] * inv);
    }
}

extern "C" void kernel_launch(void* const* d_in, const int* in_sizes, int n_in,
                              void* d_out, int out_size, void* d_ws, size_t ws_size,
                              hipStream_t stream) {
    const void* x  = d_in[0];
    const void* wq = d_in[1];
    const void* wk = d_in[2];
    const void* wv = d_in[3];
    const void* wo = d_in[4];

    char* ws = (char*)d_ws;
    unsigned short* WT  = (unsigned short*)(ws);                        // 3x1024x1024 bf16
    unsigned short* WoT = (unsigned short*)(ws + 6291456);              // 1024x1024 bf16
    float2*         tab = (float2*)(ws + 8388608);                      // 2048x32 float2
    int*            flg = (int*)(ws + 8912896);                         // dtype flag
    unsigned short* xb  = (unsigned short*)(ws + 8913920);              // 16 MB bf16 x
    unsigned short* Qb  = (unsigned short*)(ws + 8913920 + 16777216ull);
    unsigned short* Kb  = (unsigned short*)(ws + 8913920 + 2ull * 16777216);
    unsigned short* Vb  = (unsigned short*)(ws + 8913920 + 3ull * 16777216);
    unsigned short* A2  = xb;  // alias: xb dead after QKV GEMM

    detect_k<<<1, 256, 0, stream>>>((const unsigned short*)x, flg);

    dim3 tb(32, 8);
    transpose_k<<<dim3(32, 32), tb, 0, stream>>>(wq, WT, flg);
    transpose_k<<<dim3(32, 32), tb, 0, stream>>>(wk, WT + 1048576, flg);
    transpose_k<<<dim3(32, 32), tb, 0, stream>>>(wv, WT + 2097152, flg);
    transpose_k<<<dim3(32, 32), tb, 0, stream>>>(wo, WoT, flg);
    rope_tab_k<<<256, 256, 0, stream>>>(tab);
    cvt_x_k<<<(8388608 + 255) / 256, 256, 0, stream>>>(x, xb, flg, 8388608);

    gemm_bt<1><<<dim3(24, 64), 256, 0, stream>>>(xb, WT, Qb, Kb, Vb, tab, flg);
    flash_k<<<dim3(64, 32), 256, 0, stream>>>(Qb, Kb, Vb, A2);
    gemm_bt<0><<<dim3(8, 64), 256, 0, stream>>>(A2, WoT, d_out, nullptr, nullptr, nullptr, flg);
}

// Round 3
// 316.066 us; speedup vs baseline: 1.6569x; 1.6569x over previous
//
#include <hip/hip_runtime.h>
#include <hip/hip_bf16.h>
#include <stdint.h>

// MHA forward, fp32/bf16 in/out auto-detected, bf16 MFMA internal. MI355X gfx950.
// detect -> cvt x / transpose W -> rope tab -> QKV GEMM (+RoPE, Q pre-scaled by 0.125*log2e,
// V written transposed (B,H,d,S)) -> flash attn (S^T orientation, 32x32x16 MFMA, no online max,
// swizzled LDS, register-dbuf prefetch) -> O-proj GEMM.

typedef __attribute__((ext_vector_type(8))) short short8;
typedef __attribute__((ext_vector_type(4))) float floatx4;
typedef __attribute__((ext_vector_type(16))) float floatx16;

#define MFMA16(a,b,c) __builtin_amdgcn_mfma_f32_16x16x32_bf16((a),(b),(c),0,0,0)
#define MFMA32(a,b,c) __builtin_amdgcn_mfma_f32_32x32x16_bf16((a),(b),(c),0,0,0)

__device__ __forceinline__ uint32_t fbits(float f){ uint32_t u; __builtin_memcpy(&u,&f,4); return u; }
__device__ __forceinline__ unsigned short f2bf(float f) {
    uint32_t u = fbits(f);
    return (unsigned short)((u + 0x7fffu + ((u>>16)&1u)) >> 16);
}
__device__ __forceinline__ float bf2f(unsigned short s){ uint32_t u = (uint32_t)s<<16; float f; __builtin_memcpy(&f,&u,4); return f; }
// pack two floats to bf16 pair (round-half-up), lo in low 16
__device__ __forceinline__ uint32_t pkbf(float lo, float hi) {
    return __builtin_amdgcn_perm(fbits(hi)+0x8000u, fbits(lo)+0x8000u, 0x07060302u);
}

__device__ __forceinline__ void load_lds16(const unsigned short* g, unsigned short* l) {
    __builtin_amdgcn_global_load_lds(
        (const __attribute__((address_space(1))) void*)g,
        (__attribute__((address_space(3))) void*)l, 16, 0, 0);
}

// ---------------- dtype detector: flag=1 if x is fp32, 0 if bf16 ----------------
__global__ void detect_k(const unsigned short* __restrict__ xr, int* __restrict__ flag) {
    int t = threadIdx.x;
    int bad = 0;
    for (int i = t; i < 4096; i += 256) {
        float v = bf2f(xr[i]);
        if (!(__builtin_fabsf(v) < 1e10f)) bad = 1;
    }
    __shared__ int r[4];
    unsigned long long m = __ballot(bad != 0);
    if ((t & 63) == 0) r[t >> 6] = (m != 0ull) ? 1 : 0;
    __syncthreads();
    if (t == 0) flag[0] = (r[0] | r[1] | r[2] | r[3]);
}

// ---------------- x convert ----------------
__global__ void cvt_x_k(const void* __restrict__ src, unsigned short* __restrict__ dst,
                        const int* __restrict__ flag, int n) {
    int i = blockIdx.x * blockDim.x + threadIdx.x;
    if (i >= n) return;
    float v = (*flag) ? ((const float*)src)[i] : bf2f(((const unsigned short*)src)[i]);
    dst[i] = f2bf(v);
}

// ---------------- weight transpose+convert ----------------
__global__ void transpose_k(const void* __restrict__ src, unsigned short* __restrict__ dst,
                            const int* __restrict__ flag) {
    __shared__ unsigned short tile[32][33];
    const int n = 1024;
    bool f32 = (*flag) != 0;
    int bx = blockIdx.x * 32, by = blockIdx.y * 32;
    int tx = threadIdx.x, ty = threadIdx.y;
#pragma unroll
    for (int j = 0; j < 32; j += 8) {
        size_t idx = (size_t)(by + ty + j) * n + bx + tx;
        float v = f32 ? ((const float*)src)[idx] : bf2f(((const unsigned short*)src)[idx]);
        tile[ty + j][tx] = f2bf(v);
    }
    __syncthreads();
#pragma unroll
    for (int j = 0; j < 32; j += 8)
        dst[(size_t)(bx + ty + j) * n + by + tx] = tile[tx][ty + j];
}

// ---------------- rope table ----------------
__global__ void rope_tab_k(float2* __restrict__ tab) {
    int i = blockIdx.x * blockDim.x + threadIdx.x;
    if (i >= 2048 * 32) return;
    int pos = i >> 5, j = i & 31;
    float freq = exp2f(-(float)(2 * j) * (1.0f / 64.0f) * 13.287712379549449f);
    float a = (float)pos * freq;
    tab[i] = make_float2(cosf(a), sinf(a));
}

// ---------------- GEMM: C(MxN) = A(MxK) * W, Bt = W^T, bf16 MFMA, K=1024 ----------------
// MODE 0: O-proj -> d_out (fp32/bf16 per flag), N=1024
// MODE 1: QKV: N=3072; Q (rope, *0.1803), K (rope), V -> transposed (B,H,d,S)
template <int MODE>
__global__ __launch_bounds__(256) void gemm_bt(
    const unsigned short* __restrict__ A,
    const unsigned short* __restrict__ Bt,
    void* __restrict__ C0,
    unsigned short* __restrict__ C1,
    unsigned short* __restrict__ C2,
    const float2* __restrict__ tab,
    const int* __restrict__ flag) {
    const int K = 1024;
    __shared__ __align__(16) unsigned short Al[128 * 32];
    __shared__ __align__(16) unsigned short Bl[128 * 32];

    int m0 = blockIdx.y * 128;
    int n0 = blockIdx.x * 128;
    int t = threadIdx.x;
    int lane = t & 63, w = t >> 6;
    int quad = lane >> 4, l15 = lane & 15;
    int wm = (w >> 1) * 64, wn = (w & 1) * 64;

    floatx4 acc[4][4];
#pragma unroll
    for (int i = 0; i < 4; i++)
#pragma unroll
        for (int j = 0; j < 4; j++) acc[i][j] = (floatx4){0.f, 0.f, 0.f, 0.f};

    for (int k0 = 0; k0 < K; k0 += 32) {
#pragma unroll
        for (int c = 0; c < 2; c++) {
            load_lds16(A + (size_t)(m0 + w * 32 + c * 16 + (lane >> 2)) * K + k0 + (lane & 3) * 8,
                       &Al[(w * 32 + c * 16) * 32]);
        }
#pragma unroll
        for (int c = 0; c < 2; c++) {
            load_lds16(Bt + (size_t)(n0 + w * 32 + c * 16 + (lane >> 2)) * K + k0 + (lane & 3) * 8,
                       &Bl[(w * 32 + c * 16) * 32]);
        }
        asm volatile("s_waitcnt vmcnt(0)" ::: "memory");
        __syncthreads();

        short8 af[4], bfr[4];
#pragma unroll
        for (int i = 0; i < 4; i++)
            af[i] = *(const short8*)&Al[(wm + i * 16 + l15) * 32 + quad * 8];
#pragma unroll
        for (int j = 0; j < 4; j++)
            bfr[j] = *(const short8*)&Bl[(wn + j * 16 + l15) * 32 + quad * 8];
#pragma unroll
        for (int i = 0; i < 4; i++)
#pragma unroll
            for (int j = 0; j < 4; j++) acc[i][j] = MFMA16(af[i], bfr[j], acc[i][j]);
        __syncthreads();
    }

    bool out_f32 = (MODE == 0) ? ((*flag) != 0) : false;
#pragma unroll
    for (int i = 0; i < 4; i++) {
#pragma unroll
        for (int j = 0; j < 4; j++) {
            int col = n0 + wn + j * 16 + l15;
            int row0 = m0 + wm + i * 16 + quad * 4;
            if (MODE == 0) {
#pragma unroll
                for (int r = 0; r < 4; r++) {
                    size_t idx = (size_t)(row0 + r) * 1024 + col;
                    if (out_f32) ((float*)C0)[idx] = acc[i][j][r];
                    else ((unsigned short*)C0)[idx] = f2bf(acc[i][j][r]);
                }
            } else {
                int which = col >> 10, nn = col & 1023;  // uniform per block
                int b = row0 >> 11, s0 = row0 & 2047;
                if (which == 2) {
                    // V^T: (B,H,64,S); 4 consecutive s per fragment column
                    int hh = nn >> 6, d = nn & 63;
                    uint32_t lo = pkbf(acc[i][j][0], acc[i][j][1]);
                    uint32_t hi = pkbf(acc[i][j][2], acc[i][j][3]);
                    *(uint64_t*)(C2 + ((size_t)((b * 16 + hh) * 64 + d)) * 2048 + s0) =
                        (uint64_t)lo | ((uint64_t)hi << 32);
                } else {
                    int d = nn & 63;
                    unsigned short* dst = (which == 0) ? (unsigned short*)C0 : C1;
                    float sc = (which == 0) ? 0.18033688011112042f : 1.0f;  // 0.125*log2(e)
#pragma unroll
                    for (int r = 0; r < 4; r++) {
                        int s = s0 + r;
                        float v = acc[i][j][r];
                        float pv = __shfl_xor(v, 1);
                        float2 cs = tab[(s << 5) + (d >> 1)];
                        float o = (d & 1) ? (v * cs.x + pv * cs.y) : (v * cs.x - pv * cs.y);
                        dst[((size_t)(b * 2048 + s)) * 1024 + nn] = f2bf(o * sc);
                    }
                }
            }
        }
    }
}

// ---------------- flash attention v2 ----------------
// grid (64, 8): x = b*16+h; y -> q-tile (big-first + pairing). Block 256 = 4 waves.
// Q-tile 256 rows; wave w owns q cols [qt*256+w*64, +64). K-tile 64.
// S^T = K·Q^T via 32x32x16 MFMA; P^T assembled in-register; O^T = V^T·P^T.
__global__ __launch_bounds__(256, 2) void flash_k(
    const unsigned short* __restrict__ Qb,
    const unsigned short* __restrict__ Kb,
    const unsigned short* __restrict__ Vt,   // (B,H,64,S)
    unsigned short* __restrict__ A2) {
    __shared__ __align__(16) unsigned short Kl[2][64 * 64];  // [kv][d] swizzled
    __shared__ __align__(16) unsigned short Vl[2][64 * 64];  // [d][kv] swizzled

    int bh = blockIdx.x;
    int y = blockIdx.y;
    int qt = (y < 4) ? (7 - y) : (y - 4);  // big tiles dispatched first; y and y+4 pair to 36 iters
    int b = bh >> 4, h = bh & 15;
    int t = threadIdx.x, lane = t & 63, w = t >> 6;
    int l31 = lane & 31, half = lane >> 5;
    size_t base = ((size_t)b * 2048) * 1024 + h * 64;
    int q0w = qt * 256 + w * 64;

    // resident Q^T B-fragments [nb][ks]
    short8 Qf[2][4];
#pragma unroll
    for (int nb = 0; nb < 2; nb++)
#pragma unroll
        for (int ks = 0; ks < 4; ks++)
            Qf[nb][ks] = *(const short8*)(Qb + base + (size_t)(q0w + nb * 32 + l31) * 1024 +
                                          ks * 16 + half * 8);

    floatx16 O[2][2];
#pragma unroll
    for (int i = 0; i < 2; i++)
#pragma unroll
        for (int j = 0; j < 2; j++) O[i][j] = (floatx16)0.0f;
    float lsum[2] = {0.f, 0.f};

    int nk = 4 * (qt + 1);

    // staging: thread -> (row=t>>2, two 16B chunks (t&3)*2+{0,1}), XOR-swizzled LDS
    int srow = t >> 2;
    const unsigned short* kg = Kb + base + (size_t)srow * 1024 + (t & 3) * 16;
    const unsigned short* vg = Vt + ((size_t)(bh * 64 + srow)) * 2048 + (t & 3) * 16;
    int sw0 = srow * 64 + ((((t & 3) * 2 + 0) ^ (srow & 7)) * 8);
    int sw1 = srow * 64 + ((((t & 3) * 2 + 1) ^ (srow & 7)) * 8);

    short8 rk0 = *(const short8*)(kg);
    short8 rk1 = *(const short8*)(kg + 8);
    short8 rv0 = *(const short8*)(vg);
    short8 rv1 = *(const short8*)(vg + 8);

    for (int kt = 0; kt < nk; kt++) {
        int k0 = kt * 64, bf = kt & 1;
        *(short8*)&Kl[bf][sw0] = rk0;
        *(short8*)&Kl[bf][sw1] = rk1;
        *(short8*)&Vl[bf][sw0] = rv0;
        *(short8*)&Vl[bf][sw1] = rv1;
        __syncthreads();
        if (kt + 1 < nk) {
            size_t ko = (size_t)(kt + 1) * 64;
            rk0 = *(const short8*)(kg + ko * 1024);
            rk1 = *(const short8*)(kg + ko * 1024 + 8);
            rv0 = *(const short8*)(vg + ko);
            rv1 = *(const short8*)(vg + ko + 8);
        }
        if (k0 < q0w + 64) {  // else: all columns masked for this wave
            // K A-frags [mb][ks]
            short8 Ka[2][4];
#pragma unroll
            for (int mb = 0; mb < 2; mb++)
#pragma unroll
                for (int ks = 0; ks < 4; ks++)
                    Ka[mb][ks] = *(const short8*)&Kl[bf][(mb * 32 + l31) * 64 +
                                                        (((ks * 2 + half) ^ (l31 & 7)) * 8)];
            floatx16 Sc[2][2];
#pragma unroll
            for (int i = 0; i < 2; i++)
#pragma unroll
                for (int j = 0; j < 2; j++) Sc[i][j] = (floatx16)0.0f;
#pragma unroll
            for (int mb = 0; mb < 2; mb++)
#pragma unroll
                for (int nb = 0; nb < 2; nb++)
#pragma unroll
                    for (int ks = 0; ks < 4; ks++)
                        Sc[mb][nb] = MFMA32(Ka[mb][ks], Qf[nb][ks], Sc[mb][nb]);

            // softmax (no max subtraction; Q pre-scaled so p = exp2(s))
            bool domask = (k0 + 63 > q0w);
            uint32_t pk[2][2][8];  // [nb][mb][pair]
#pragma unroll
            for (int mb = 0; mb < 2; mb++) {
#pragma unroll
                for (int nb = 0; nb < 2; nb++) {
                    float p[16];
#pragma unroll
                    for (int e = 0; e < 16; e++) {
                        float v = exp2f(Sc[mb][nb][e]);
                        if (domask) {
                            int kv = k0 + mb * 32 + (e & 3) + ((e >> 2) << 3) + half * 4;
                            int qq = q0w + nb * 32 + l31;
                            v = (kv > qq) ? 0.f : v;
                        }
                        lsum[nb] += v;
                        p[e] = v;
                    }
#pragma unroll
                    for (int jj = 0; jj < 8; jj++)
                        pk[nb][mb][jj] = pkbf(p[2 * jj], p[2 * jj + 1]);
                }
            }

            // V^T A-frags [db][ksg]
            short8 Va[2][4];
#pragma unroll
            for (int db = 0; db < 2; db++)
#pragma unroll
                for (int ks = 0; ks < 4; ks++)
                    Va[db][ks] = *(const short8*)&Vl[bf][(db * 32 + l31) * 64 +
                                                        (((ks * 2 + half) ^ (l31 & 7)) * 8)];
            // PV: P^T B-frags via half-wave exchange
#pragma unroll
            for (int mb = 0; mb < 2; mb++) {
#pragma unroll
                for (int ks2 = 0; ks2 < 2; ks2++) {
                    int ksg = mb * 2 + ks2;
#pragma unroll
                    for (int nb = 0; nb < 2; nb++) {
                        uint32_t p0 = pk[nb][mb][4 * ks2 + 0];
                        uint32_t p1 = pk[nb][mb][4 * ks2 + 1];
                        uint32_t p2 = pk[nb][mb][4 * ks2 + 2];
                        uint32_t p3 = pk[nb][mb][4 * ks2 + 3];
                        uint32_t u = half ? p0 : p2;
                        uint32_t v2 = half ? p1 : p3;
                        uint32_t ya = (uint32_t)__shfl_xor((int)u, 32);
                        uint32_t yb = (uint32_t)__shfl_xor((int)v2, 32);
                        union { short8 s; uint32_t q[4]; } bb;
                        bb.q[0] = half ? ya : p0;
                        bb.q[1] = half ? yb : p1;
                        bb.q[2] = half ? p2 : ya;
                        bb.q[3] = half ? p3 : yb;
#pragma unroll
                        for (int db = 0; db < 2; db++)
                            O[db][nb] = MFMA32(Va[db][ksg], bb.s, O[db][nb]);
                    }
                }
            }
        }
    }

    // epilogue: O^T frags -> A2 (B,S,D) bf16, divide by l
    float inv[2];
#pragma unroll
    for (int nb = 0; nb < 2; nb++) {
        float tot = lsum[nb] + __shfl_xor(lsum[nb], 32);
        inv[nb] = 1.0f / tot;
    }
#pragma unroll
    for (int db = 0; db < 2; db++) {
#pragma unroll
        for (int nb = 0; nb < 2; nb++) {
            int scol = q0w + nb * 32 + l31;
            unsigned short* op = A2 + base + (size_t)scol * 1024;
#pragma unroll
            for (int g = 0; g < 4; g++) {
                int d0 = db * 32 + half * 4 + g * 8;
                float v0 = O[db][nb][g * 4 + 0] * inv[nb];
                float v1 = O[db][nb][g * 4 + 1] * inv[nb];
                float v2 = O[db][nb][g * 4 + 2] * inv[nb];
                float v3 = O[db][nb][g * 4 + 3] * inv[nb];
                uint32_t lo = pkbf(v0, v1), hi = pkbf(v2, v3);
                *(uint64_t*)(op + d0) = (uint64_t)lo | ((uint64_t)hi << 32);
            }
        }
    }
}

extern "C" void kernel_launch(void* const* d_in, const int* in_sizes, int n_in,
                              void* d_out, int out_size, void* d_ws, size_t ws_size,
                              hipStream_t stream) {
    const void* x  = d_in[0];
    const void* wq = d_in[1];
    const void* wk = d_in[2];
    const void* wv = d_in[3];
    const void* wo = d_in[4];

    char* ws = (char*)d_ws;
    unsigned short* WT  = (unsigned short*)(ws);                        // 3x1024x1024 bf16
    unsigned short* WoT = (unsigned short*)(ws + 6291456);              // 1024x1024 bf16
    float2*         tab = (float2*)(ws + 8388608);                      // 2048x32 float2
    int*            flg = (int*)(ws + 8912896);
    unsigned short* xb  = (unsigned short*)(ws + 8913920);              // 16 MB bf16 x
    unsigned short* Qb  = (unsigned short*)(ws + 8913920 + 16777216ull);
    unsigned short* Kb  = (unsigned short*)(ws + 8913920 + 2ull * 16777216);
    unsigned short* Vt  = (unsigned short*)(ws + 8913920 + 3ull * 16777216);  // (B,H,64,S)
    unsigned short* A2  = xb;  // alias: xb dead after QKV GEMM

    detect_k<<<1, 256, 0, stream>>>((const unsigned short*)x, flg);

    dim3 tb(32, 8);
    transpose_k<<<dim3(32, 32), tb, 0, stream>>>(wq, WT, flg);
    transpose_k<<<dim3(32, 32), tb, 0, stream>>>(wk, WT + 1048576, flg);
    transpose_k<<<dim3(32, 32), tb, 0, stream>>>(wv, WT + 2097152, flg);
    transpose_k<<<dim3(32, 32), tb, 0, stream>>>(wo, WoT, flg);
    rope_tab_k<<<256, 256, 0, stream>>>(tab);
    cvt_x_k<<<(8388608 + 255) / 256, 256, 0, stream>>>(x, xb, flg, 8388608);

    gemm_bt<1><<<dim3(24, 64), 256, 0, stream>>>(xb, WT, Qb, Kb, Vt, tab, flg);
    flash_k<<<dim3(64, 8), 256, 0, stream>>>(Qb, Kb, Vt, A2);
    gemm_bt<0><<<dim3(8, 64), 256, 0, stream>>>(A2, WoT, d_out, nullptr, nullptr, nullptr, flg);
}

// Round 6
// 300.318 us; speedup vs baseline: 1.7438x; 1.0524x over previous
//
#include <hip/hip_runtime.h>
#include <hip/hip_bf16.h>
#include <stdint.h>

// MHA forward, fp32/bf16 in/out auto-detected, bf16 MFMA internal. MI355X gfx950.
// detect -> fused prep (W transpose, rope tab, x cvt) -> QKV GEMM (+RoPE, Q pre-scaled,
// V transposed (B,H,d,S)) -> flash attn (S^T orientation, 32x32x16 MFMA) -> O-proj GEMM.
// NOTE: gemm_bt is the round-3 hardware-verified version (BK=32, scalar epilogue stores).

typedef __attribute__((ext_vector_type(8))) short short8;
typedef __attribute__((ext_vector_type(4))) float floatx4;
typedef __attribute__((ext_vector_type(16))) float floatx16;

#define MFMA16(a,b,c) __builtin_amdgcn_mfma_f32_16x16x32_bf16((a),(b),(c),0,0,0)
#define MFMA32(a,b,c) __builtin_amdgcn_mfma_f32_32x32x16_bf16((a),(b),(c),0,0,0)

__device__ __forceinline__ uint32_t fbits(float f){ uint32_t u; __builtin_memcpy(&u,&f,4); return u; }
__device__ __forceinline__ unsigned short f2bf(float f) {
    uint32_t u = fbits(f);
    return (unsigned short)((u + 0x7fffu + ((u>>16)&1u)) >> 16);
}
__device__ __forceinline__ float bf2f(unsigned short s){ uint32_t u = (uint32_t)s<<16; float f; __builtin_memcpy(&f,&u,4); return f; }
// pack two floats to bf16 pair (round-half-up), lo in low 16
__device__ __forceinline__ uint32_t pkbf(float lo, float hi) {
    return __builtin_amdgcn_perm(fbits(hi)+0x8000u, fbits(lo)+0x8000u, 0x07060302u);
}

__device__ __forceinline__ void load_lds16(const unsigned short* g, unsigned short* l) {
    __builtin_amdgcn_global_load_lds(
        (const __attribute__((address_space(1))) void*)g,
        (__attribute__((address_space(3))) void*)l, 16, 0, 0);
}

// ---------------- dtype detector: flag=1 if x is fp32, 0 if bf16 ----------------
__global__ void detect_k(const unsigned short* __restrict__ xr, int* __restrict__ flag) {
    int t = threadIdx.x;
    int bad = 0;
    for (int i = t; i < 4096; i += 256) {
        float v = bf2f(xr[i]);
        if (!(__builtin_fabsf(v) < 1e10f)) bad = 1;
    }
    __shared__ int r[4];
    unsigned long long m = __ballot(bad != 0);
    if ((t & 63) == 0) r[t >> 6] = (m != 0ull) ? 1 : 0;
    __syncthreads();
    if (t == 0) flag[0] = (r[0] | r[1] | r[2] | r[3]);
}

// ---------------- fused prep: W transposes (blk<4096), rope tab, x convert ----------------
__global__ __launch_bounds__(256) void prep_k(
    const void* __restrict__ x,
    const void* __restrict__ wq, const void* __restrict__ wk,
    const void* __restrict__ wv, const void* __restrict__ wo,
    unsigned short* __restrict__ WT, unsigned short* __restrict__ WoT,
    float2* __restrict__ tab, unsigned short* __restrict__ xb,
    const int* __restrict__ flag) {
    int blk = blockIdx.x, t = threadIdx.x;
    bool f32 = (*flag) != 0;
    if (blk < 4096) {
        __shared__ unsigned short tile[32][33];
        int mat = blk >> 10, r = blk & 1023;
        const void* src = (mat == 0) ? wq : (mat == 1) ? wk : (mat == 2) ? wv : wo;
        unsigned short* dst = (mat < 3) ? (WT + (size_t)mat * 1048576) : WoT;
        int bx = (r & 31) * 32, by = (r >> 5) * 32;
        int tx = t & 31, ty = t >> 5;  // 32 x 8
#pragma unroll
        for (int j = 0; j < 32; j += 8) {
            size_t idx = (size_t)(by + ty + j) * 1024 + bx + tx;
            float v = f32 ? ((const float*)src)[idx] : bf2f(((const unsigned short*)src)[idx]);
            tile[ty + j][tx] = f2bf(v);
        }
        __syncthreads();
#pragma unroll
        for (int j = 0; j < 32; j += 8)
            dst[(size_t)(bx + ty + j) * 1024 + by + tx] = tile[tx][ty + j];
    } else if (blk < 4352) {
        int i = (blk - 4096) * 256 + t;  // 65536 entries
        int pos = i >> 5, j = i & 31;
        float freq = exp2f(-(float)(2 * j) * (1.0f / 64.0f) * 13.287712379549449f);
        float a = (float)pos * freq;
        tab[i] = make_float2(cosf(a), sinf(a));
    } else {
        size_t base = (size_t)(blk - 4352) * 2048 + (size_t)t * 8;
        if (f32) {
            const float4* s4 = (const float4*)((const float*)x + base);
            float4 a = s4[0], b = s4[1];
            uint4 o;
            o.x = pkbf(a.x, a.y); o.y = pkbf(a.z, a.w);
            o.z = pkbf(b.x, b.y); o.w = pkbf(b.z, b.w);
            *(uint4*)(xb + base) = o;
        } else {
            *(uint4*)(xb + base) = *(const uint4*)((const unsigned short*)x + base);
        }
    }
}

// ---------------- GEMM (round-3 verified): C = A * W, Bt = W^T, bf16 MFMA, K=1024, BK=32 ----
// MODE 0: O-proj -> d_out (fp32/bf16 per flag), N=1024
// MODE 1: QKV: N=3072; Q (rope, *0.18034), K (rope), V -> transposed (B,H,d,S)
template <int MODE>
__global__ __launch_bounds__(256) void gemm_bt(
    const unsigned short* __restrict__ A,
    const unsigned short* __restrict__ Bt,
    void* __restrict__ C0,
    unsigned short* __restrict__ C1,
    unsigned short* __restrict__ C2,
    const float2* __restrict__ tab,
    const int* __restrict__ flag) {
    const int K = 1024;
    __shared__ __align__(16) unsigned short Al[128 * 32];
    __shared__ __align__(16) unsigned short Bl[128 * 32];

    int m0 = blockIdx.y * 128;
    int n0 = blockIdx.x * 128;
    int t = threadIdx.x;
    int lane = t & 63, w = t >> 6;
    int quad = lane >> 4, l15 = lane & 15;
    int wm = (w >> 1) * 64, wn = (w & 1) * 64;

    floatx4 acc[4][4];
#pragma unroll
    for (int i = 0; i < 4; i++)
#pragma unroll
        for (int j = 0; j < 4; j++) acc[i][j] = (floatx4){0.f, 0.f, 0.f, 0.f};

    for (int k0 = 0; k0 < K; k0 += 32) {
#pragma unroll
        for (int c = 0; c < 2; c++) {
            load_lds16(A + (size_t)(m0 + w * 32 + c * 16 + (lane >> 2)) * K + k0 + (lane & 3) * 8,
                       &Al[(w * 32 + c * 16) * 32]);
        }
#pragma unroll
        for (int c = 0; c < 2; c++) {
            load_lds16(Bt + (size_t)(n0 + w * 32 + c * 16 + (lane >> 2)) * K + k0 + (lane & 3) * 8,
                       &Bl[(w * 32 + c * 16) * 32]);
        }
        asm volatile("s_waitcnt vmcnt(0)" ::: "memory");
        __syncthreads();

        short8 af[4], bfr[4];
#pragma unroll
        for (int i = 0; i < 4; i++)
            af[i] = *(const short8*)&Al[(wm + i * 16 + l15) * 32 + quad * 8];
#pragma unroll
        for (int j = 0; j < 4; j++)
            bfr[j] = *(const short8*)&Bl[(wn + j * 16 + l15) * 32 + quad * 8];
#pragma unroll
        for (int i = 0; i < 4; i++)
#pragma unroll
            for (int j = 0; j < 4; j++) acc[i][j] = MFMA16(af[i], bfr[j], acc[i][j]);
        __syncthreads();
    }

    bool out_f32 = (MODE == 0) ? ((*flag) != 0) : false;
#pragma unroll
    for (int i = 0; i < 4; i++) {
#pragma unroll
        for (int j = 0; j < 4; j++) {
            int col = n0 + wn + j * 16 + l15;
            int row0 = m0 + wm + i * 16 + quad * 4;
            if (MODE == 0) {
#pragma unroll
                for (int r = 0; r < 4; r++) {
                    size_t idx = (size_t)(row0 + r) * 1024 + col;
                    if (out_f32) ((float*)C0)[idx] = acc[i][j][r];
                    else ((unsigned short*)C0)[idx] = f2bf(acc[i][j][r]);
                }
            } else {
                int which = col >> 10, nn = col & 1023;  // uniform per block
                int b = row0 >> 11, s0 = row0 & 2047;
                if (which == 2) {
                    // V^T: (B,H,64,S); 4 consecutive s per fragment column
                    int hh = nn >> 6, d = nn & 63;
                    uint32_t lo = pkbf(acc[i][j][0], acc[i][j][1]);
                    uint32_t hi = pkbf(acc[i][j][2], acc[i][j][3]);
                    *(uint64_t*)(C2 + ((size_t)((b * 16 + hh) * 64 + d)) * 2048 + s0) =
                        (uint64_t)lo | ((uint64_t)hi << 32);
                } else {
                    int d = nn & 63;
                    unsigned short* dst = (which == 0) ? (unsigned short*)C0 : C1;
                    float sc = (which == 0) ? 0.18033688011112042f : 1.0f;  // 0.125*log2(e)
#pragma unroll
                    for (int r = 0; r < 4; r++) {
                        int s = s0 + r;
                        float v = acc[i][j][r];
                        float pv = __shfl_xor(v, 1);
                        float2 cs = tab[(s << 5) + (d >> 1)];
                        float o = (d & 1) ? (v * cs.x + pv * cs.y) : (v * cs.x - pv * cs.y);
                        dst[((size_t)(b * 2048 + s)) * 1024 + nn] = f2bf(o * sc);
                    }
                }
            }
        }
    }
}

// ---------------- flash attention v2 (round-3 verified + lsum ILP tree) ----------------
// grid (64, 8): x = b*16+h; y -> q-tile (big-first + pairing). Block 256 = 4 waves.
// Q-tile 256 rows; wave w owns q cols [qt*256+w*64, +64). K-tile 64.
// S^T = K·Q^T via 32x32x16 MFMA; P^T assembled in-register; O^T = V^T·P^T.
__global__ __launch_bounds__(256, 2) void flash_k(
    const unsigned short* __restrict__ Qb,
    const unsigned short* __restrict__ Kb,
    const unsigned short* __restrict__ Vt,   // (B,H,64,S)
    unsigned short* __restrict__ A2) {
    __shared__ __align__(16) unsigned short Kl[2][64 * 64];  // [kv][d] swizzled
    __shared__ __align__(16) unsigned short Vl[2][64 * 64];  // [d][kv] swizzled

    int bh = blockIdx.x;
    int y = blockIdx.y;
    int qt = (y < 4) ? (7 - y) : (y - 4);  // big tiles first; y and y+4 pair to 36 iters
    int b = bh >> 4, h = bh & 15;
    int t = threadIdx.x, lane = t & 63, w = t >> 6;
    int l31 = lane & 31, half = lane >> 5;
    size_t base = ((size_t)b * 2048) * 1024 + h * 64;
    int q0w = qt * 256 + w * 64;

    // resident Q^T B-fragments [nb][ks]
    short8 Qf[2][4];
#pragma unroll
    for (int nb = 0; nb < 2; nb++)
#pragma unroll
        for (int ks = 0; ks < 4; ks++)
            Qf[nb][ks] = *(const short8*)(Qb + base + (size_t)(q0w + nb * 32 + l31) * 1024 +
                                          ks * 16 + half * 8);

    floatx16 O[2][2];
#pragma unroll
    for (int i = 0; i < 2; i++)
#pragma unroll
        for (int j = 0; j < 2; j++) O[i][j] = (floatx16)0.0f;
    float lsum[2] = {0.f, 0.f};

    int nk = 4 * (qt + 1);

    int srow = t >> 2;
    const unsigned short* kg = Kb + base + (size_t)srow * 1024 + (t & 3) * 16;
    const unsigned short* vg = Vt + ((size_t)(bh * 64 + srow)) * 2048 + (t & 3) * 16;
    int sw0 = srow * 64 + ((((t & 3) * 2 + 0) ^ (srow & 7)) * 8);
    int sw1 = srow * 64 + ((((t & 3) * 2 + 1) ^ (srow & 7)) * 8);

    short8 rk0 = *(const short8*)(kg);
    short8 rk1 = *(const short8*)(kg + 8);
    short8 rv0 = *(const short8*)(vg);
    short8 rv1 = *(const short8*)(vg + 8);

    for (int kt = 0; kt < nk; kt++) {
        int k0 = kt * 64, bf = kt & 1;
        *(short8*)&Kl[bf][sw0] = rk0;
        *(short8*)&Kl[bf][sw1] = rk1;
        *(short8*)&Vl[bf][sw0] = rv0;
        *(short8*)&Vl[bf][sw1] = rv1;
        __syncthreads();
        if (kt + 1 < nk) {
            size_t ko = (size_t)(kt + 1) * 64;
            rk0 = *(const short8*)(kg + ko * 1024);
            rk1 = *(const short8*)(kg + ko * 1024 + 8);
            rv0 = *(const short8*)(vg + ko);
            rv1 = *(const short8*)(vg + ko + 8);
        }
        if (k0 < q0w + 64) {
            short8 Ka[2][4];
#pragma unroll
            for (int mb = 0; mb < 2; mb++)
#pragma unroll
                for (int ks = 0; ks < 4; ks++)
                    Ka[mb][ks] = *(const short8*)&Kl[bf][(mb * 32 + l31) * 64 +
                                                        (((ks * 2 + half) ^ (l31 & 7)) * 8)];
            floatx16 Sc[2][2];
#pragma unroll
            for (int i = 0; i < 2; i++)
#pragma unroll
                for (int j = 0; j < 2; j++) Sc[i][j] = (floatx16)0.0f;
#pragma unroll
            for (int mb = 0; mb < 2; mb++)
#pragma unroll
                for (int nb = 0; nb < 2; nb++)
#pragma unroll
                    for (int ks = 0; ks < 4; ks++)
                        Sc[mb][nb] = MFMA32(Ka[mb][ks], Qf[nb][ks], Sc[mb][nb]);

            bool domask = (k0 + 63 > q0w);
            uint32_t pk[2][2][8];  // [nb][mb][pair]
#pragma unroll
            for (int mb = 0; mb < 2; mb++) {
#pragma unroll
                for (int nb = 0; nb < 2; nb++) {
                    float p[16];
#pragma unroll
                    for (int e = 0; e < 16; e++) {
                        float v = exp2f(Sc[mb][nb][e]);
                        if (domask) {
                            int kv = k0 + mb * 32 + (e & 3) + ((e >> 2) << 3) + half * 4;
                            int qq = q0w + nb * 32 + l31;
                            v = (kv > qq) ? 0.f : v;
                        }
                        p[e] = v;
                    }
                    // ILP sum tree (arithmetically = serial sum, 4x shorter dep chain)
                    float t0 = (p[0] + p[1]) + (p[2] + p[3]);
                    float t1 = (p[4] + p[5]) + (p[6] + p[7]);
                    float t2 = (p[8] + p[9]) + (p[10] + p[11]);
                    float t3 = (p[12] + p[13]) + (p[14] + p[15]);
                    lsum[nb] += (t0 + t1) + (t2 + t3);
#pragma unroll
                    for (int jj = 0; jj < 8; jj++)
                        pk[nb][mb][jj] = pkbf(p[2 * jj], p[2 * jj + 1]);
                }
            }

            short8 Va[2][4];
#pragma unroll
            for (int db = 0; db < 2; db++)
#pragma unroll
                for (int ks = 0; ks < 4; ks++)
                    Va[db][ks] = *(const short8*)&Vl[bf][(db * 32 + l31) * 64 +
                                                        (((ks * 2 + half) ^ (l31 & 7)) * 8)];
#pragma unroll
            for (int mb = 0; mb < 2; mb++) {
#pragma unroll
                for (int ks2 = 0; ks2 < 2; ks2++) {
                    int ksg = mb * 2 + ks2;
#pragma unroll
                    for (int nb = 0; nb < 2; nb++) {
                        uint32_t p0 = pk[nb][mb][4 * ks2 + 0];
                        uint32_t p1 = pk[nb][mb][4 * ks2 + 1];
                        uint32_t p2 = pk[nb][mb][4 * ks2 + 2];
                        uint32_t p3 = pk[nb][mb][4 * ks2 + 3];
                        uint32_t u = half ? p0 : p2;
                        uint32_t v2 = half ? p1 : p3;
                        uint32_t ya = (uint32_t)__shfl_xor((int)u, 32);
                        uint32_t yb = (uint32_t)__shfl_xor((int)v2, 32);
                        union { short8 s; uint32_t q[4]; } bb;
                        bb.q[0] = half ? ya : p0;
                        bb.q[1] = half ? yb : p1;
                        bb.q[2] = half ? p2 : ya;
                        bb.q[3] = half ? p3 : yb;
#pragma unroll
                        for (int db = 0; db < 2; db++)
                            O[db][nb] = MFMA32(Va[db][ksg], bb.s, O[db][nb]);
                    }
                }
            }
        }
    }

    float inv[2];
#pragma unroll
    for (int nb = 0; nb < 2; nb++) {
        float tot = lsum[nb] + __shfl_xor(lsum[nb], 32);
        inv[nb] = 1.0f / tot;
    }
#pragma unroll
    for (int db = 0; db < 2; db++) {
#pragma unroll
        for (int nb = 0; nb < 2; nb++) {
            int scol = q0w + nb * 32 + l31;
            unsigned short* op = A2 + base + (size_t)scol * 1024;
#pragma unroll
            for (int g = 0; g < 4; g++) {
                int d0 = db * 32 + half * 4 + g * 8;
                float v0 = O[db][nb][g * 4 + 0] * inv[nb];
                float v1 = O[db][nb][g * 4 + 1] * inv[nb];
                float v2 = O[db][nb][g * 4 + 2] * inv[nb];
                float v3 = O[db][nb][g * 4 + 3] * inv[nb];
                uint32_t lo = pkbf(v0, v1), hi = pkbf(v2, v3);
                *(uint64_t*)(op + d0) = (uint64_t)lo | ((uint64_t)hi << 32);
            }
        }
    }
}

extern "C" void kernel_launch(void* const* d_in, const int* in_sizes, int n_in,
                              void* d_out, int out_size, void* d_ws, size_t ws_size,
                              hipStream_t stream) {
    const void* x  = d_in[0];
    const void* wq = d_in[1];
    const void* wk = d_in[2];
    const void* wv = d_in[3];
    const void* wo = d_in[4];

    char* ws = (char*)d_ws;
    unsigned short* WT  = (unsigned short*)(ws);                        // 3x1024x1024 bf16
    unsigned short* WoT = (unsigned short*)(ws + 6291456);              // 1024x1024 bf16
    float2*         tab = (float2*)(ws + 8388608);                      // 2048x32 float2
    int*            flg = (int*)(ws + 8912896);
    unsigned short* xb  = (unsigned short*)(ws + 8913920);              // 16 MB bf16 x
    unsigned short* Qb  = (unsigned short*)(ws + 8913920 + 16777216ull);
    unsigned short* Kb  = (unsigned short*)(ws + 8913920 + 2ull * 16777216);
    unsigned short* Vt  = (unsigned short*)(ws + 8913920 + 3ull * 16777216);  // (B,H,64,S)
    unsigned short* A2  = xb;  // alias: xb dead after QKV GEMM

    detect_k<<<1, 256, 0, stream>>>((const unsigned short*)x, flg);
    prep_k<<<8448, 256, 0, stream>>>(x, wq, wk, wv, wo, WT, WoT, tab, xb, flg);

    gemm_bt<1><<<dim3(24, 64), 256, 0, stream>>>(xb, WT, Qb, Kb, Vt, tab, flg);
    flash_k<<<dim3(64, 8), 256, 0, stream>>>(Qb, Kb, Vt, A2);
    gemm_bt<0><<<dim3(8, 64), 256, 0, stream>>>(A2, WoT, d_out, nullptr, nullptr, nullptr, flg);
}